// Round 1
// baseline (96.114 us; speedup 1.0000x reference)
//
#include <hip/hip_runtime.h>

// NovelKQRAttention — algebraically collapsed.
// energy = a[...,q,None] + b[...,None,k]; softmax over k => a cancels,
// attn = softmax_k(b) independent of q => deform-conv path is dead,
// attention output constant over spatial dims.
//
// Pipeline:
//   kb[h,c]   = sum_e appr_bias[h*64+e] * key_w[h*64+e, c]          (9x576)
//   b[n,h,k]  = sum_c kb[h,c] * x_kv[n,c,k]        x_kv = x[:,:,::2,::2]
//   p[n,h,k]  = softmax_k(b)
//   wx[n,h,c] = sum_k p[n,h,k] * x_kv[n,c,k]
//   ov[n,o]   = sum_c value_w[o,c] * wx[n, o/64, c]
//   po[n,o]   = sum_c proj_w[o,c] * ov[n,c] + proj_b[o]
//   out[n,o,h,w] = gamma * po[n,o] + x[n,o,h,w]

#define CCH 576
#define NHEADS 9
#define HW 4096   // 64*64
#define KHW 1024  // 32*32
#define WID 64

// ws float offsets
#define WS_KB    0         // 9*576            = 5184
#define WS_BPART 5184      // 2*4*9*1024       = 73728
#define WS_P     78912     // 2*9*1024         = 18432
#define WS_WX    97344     // 2*9*576          = 10368
#define WS_OV    107712    // 2*576            = 1152
#define WS_PO    108864    // 2*576            = 1152
// total 110016 floats = 440 KB

__global__ void k_kb(const float* __restrict__ key_w, const float* __restrict__ appr_bias,
                     float* __restrict__ kb) {
    int h = blockIdx.x;        // 0..8
    int tid = threadIdx.x;     // 64 threads
    __shared__ float ab[64];
    ab[tid] = appr_bias[h * 64 + tid];
    __syncthreads();
    for (int c = tid; c < CCH; c += 64) {
        float s = 0.f;
        #pragma unroll 8
        for (int e = 0; e < 64; ++e)
            s += ab[e] * key_w[(size_t)(h * 64 + e) * CCH + c];
        kb[h * CCH + c] = s;
    }
}

// grid (4 kblk, 2 n, 4 chunk), block 256. Partial b over a 144-channel chunk.
__global__ void k_bpart(const float* __restrict__ x, const float* __restrict__ kb,
                        float* __restrict__ bpart) {
    int k  = blockIdx.x * 256 + threadIdx.x;   // 0..1023
    int n  = blockIdx.y;
    int ch = blockIdx.z;
    int c0 = ch * 144;
    __shared__ float kbs[NHEADS][144];
    for (int i = threadIdx.x; i < NHEADS * 144; i += 256) {
        int h = i / 144, cl = i % 144;
        kbs[h][cl] = kb[h * CCH + c0 + cl];
    }
    __syncthreads();
    int ky = k >> 5, kx = k & 31;
    const float* xb = x + (size_t)n * CCH * HW + (size_t)(ky * 2) * WID + kx * 2;
    float acc[NHEADS];
    #pragma unroll
    for (int h = 0; h < NHEADS; ++h) acc[h] = 0.f;
    for (int cl = 0; cl < 144; ++cl) {
        float xv = xb[(size_t)(c0 + cl) * HW];
        #pragma unroll
        for (int h = 0; h < NHEADS; ++h) acc[h] += kbs[h][cl] * xv;
    }
    #pragma unroll
    for (int h = 0; h < NHEADS; ++h)
        bpart[(((size_t)n * 4 + ch) * NHEADS + h) * KHW + k] = acc[h];
}

// grid 18 (= n*9), block 256. Sum 4 chunks, softmax over k=1024, write p.
__global__ void k_softmax(const float* __restrict__ bpart, float* __restrict__ p) {
    int nh = blockIdx.x;
    int n = nh / NHEADS, h = nh % NHEADS;
    int tid = threadIdx.x;
    int wave = tid >> 6, lane = tid & 63;
    float s[4];
    #pragma unroll
    for (int j = 0; j < 4; ++j) {
        int k = tid + j * 256;
        float v = 0.f;
        #pragma unroll
        for (int ch = 0; ch < 4; ++ch)
            v += bpart[(((size_t)n * 4 + ch) * NHEADS + h) * KHW + k];
        s[j] = v;
    }
    float m = fmaxf(fmaxf(s[0], s[1]), fmaxf(s[2], s[3]));
    #pragma unroll
    for (int off = 32; off >= 1; off >>= 1)
        m = fmaxf(m, __shfl_xor(m, off, 64));
    __shared__ float redm[4];
    if (lane == 0) redm[wave] = m;
    __syncthreads();
    m = fmaxf(fmaxf(redm[0], redm[1]), fmaxf(redm[2], redm[3]));
    float e[4], lsum = 0.f;
    #pragma unroll
    for (int j = 0; j < 4; ++j) { e[j] = __expf(s[j] - m); lsum += e[j]; }
    #pragma unroll
    for (int off = 32; off >= 1; off >>= 1)
        lsum += __shfl_xor(lsum, off, 64);
    __shared__ float reds[4];
    if (lane == 0) reds[wave] = lsum;
    __syncthreads();
    float inv = 1.f / (reds[0] + reds[1] + reds[2] + reds[3]);
    #pragma unroll
    for (int j = 0; j < 4; ++j)
        p[(size_t)nh * KHW + tid + j * 256] = e[j] * inv;
}

// grid (36 c-tiles, 2 n), block 256 (4 waves). Each wave: 4 channels, reduce over k.
__global__ void k_wx(const float* __restrict__ x, const float* __restrict__ p,
                     float* __restrict__ wx) {
    int n  = blockIdx.y;
    int c0 = blockIdx.x * 16;
    __shared__ float ps[NHEADS][KHW];  // 36 KB
    for (int i = threadIdx.x; i < NHEADS * KHW; i += 256)
        ps[0][i] = p[(size_t)n * NHEADS * KHW + i];
    __syncthreads();
    int wave = threadIdx.x >> 6, lane = threadIdx.x & 63;
    for (int j = 0; j < 4; ++j) {
        int c = c0 + wave * 4 + j;
        const float* xb = x + ((size_t)n * CCH + c) * HW;
        float acc[NHEADS];
        #pragma unroll
        for (int h = 0; h < NHEADS; ++h) acc[h] = 0.f;
        for (int k = lane; k < KHW; k += 64) {
            int ky = k >> 5, kx = k & 31;
            float xv = xb[(size_t)(ky * 2) * WID + kx * 2];
            #pragma unroll
            for (int h = 0; h < NHEADS; ++h) acc[h] += ps[h][k] * xv;
        }
        #pragma unroll
        for (int h = 0; h < NHEADS; ++h) {
            float v = acc[h];
            #pragma unroll
            for (int off = 32; off >= 1; off >>= 1)
                v += __shfl_xor(v, off, 64);
            if (lane == 0) wx[((size_t)n * NHEADS + h) * CCH + c] = v;
        }
    }
}

// one wave per output element; grid 288, block 256 (4 waves)
__global__ void k_ov(const float* __restrict__ value_w, const float* __restrict__ wx,
                     float* __restrict__ ov) {
    int g = blockIdx.x * 4 + (threadIdx.x >> 6);   // 0..1151
    int lane = threadIdx.x & 63;
    int n = g / CCH, o = g % CCH;
    int h = o >> 6;
    float acc = 0.f;
    for (int c = lane; c < CCH; c += 64)
        acc += value_w[(size_t)o * CCH + c] * wx[((size_t)n * NHEADS + h) * CCH + c];
    #pragma unroll
    for (int off = 32; off >= 1; off >>= 1)
        acc += __shfl_xor(acc, off, 64);
    if (lane == 0) ov[n * CCH + o] = acc;
}

__global__ void k_po(const float* __restrict__ proj_w, const float* __restrict__ proj_b,
                     const float* __restrict__ ov, float* __restrict__ po) {
    int g = blockIdx.x * 4 + (threadIdx.x >> 6);
    int lane = threadIdx.x & 63;
    int n = g / CCH, o = g % CCH;
    float acc = 0.f;
    for (int c = lane; c < CCH; c += 64)
        acc += proj_w[(size_t)o * CCH + c] * ov[n * CCH + c];
    #pragma unroll
    for (int off = 32; off >= 1; off >>= 1)
        acc += __shfl_xor(acc, off, 64);
    if (lane == 0) po[n * CCH + o] = acc + proj_b[o];
}

// out[n,o,:,:] = gamma*po[n,o] + x ; vectorized float4 grid-stride
__global__ void k_final(const float* __restrict__ x, const float* __restrict__ po,
                        const float* __restrict__ gamma, float* __restrict__ out) {
    const size_t total4 = (size_t)2 * CCH * HW / 4;   // 1179648
    float g = gamma[0];
    const float4* x4 = (const float4*)x;
    float4* o4 = (float4*)out;
    for (size_t i = (size_t)blockIdx.x * blockDim.x + threadIdx.x; i < total4;
         i += (size_t)gridDim.x * blockDim.x) {
        int no = (int)((i * 4) / HW);       // n*CCH + o
        float base = g * po[no];
        float4 v = x4[i];
        v.x += base; v.y += base; v.z += base; v.w += base;
        o4[i] = v;
    }
}

extern "C" void kernel_launch(void* const* d_in, const int* in_sizes, int n_in,
                              void* d_out, int out_size, void* d_ws, size_t ws_size,
                              hipStream_t stream) {
    const float* x         = (const float*)d_in[0];
    const float* key_w     = (const float*)d_in[1];
    // d_in[2] offset_w, d_in[3] dconv_w, d_in[8] appr_bias_q: dead path (a cancels in softmax)
    const float* value_w   = (const float*)d_in[4];
    const float* proj_w    = (const float*)d_in[5];
    const float* proj_b    = (const float*)d_in[6];
    const float* appr_bias = (const float*)d_in[7];
    const float* gamma     = (const float*)d_in[9];
    float* out = (float*)d_out;

    float* ws    = (float*)d_ws;
    float* kb    = ws + WS_KB;
    float* bpart = ws + WS_BPART;
    float* p     = ws + WS_P;
    float* wx    = ws + WS_WX;
    float* ov    = ws + WS_OV;
    float* po    = ws + WS_PO;

    k_kb     <<<NHEADS, 64, 0, stream>>>(key_w, appr_bias, kb);
    k_bpart  <<<dim3(4, 2, 4), 256, 0, stream>>>(x, kb, bpart);
    k_softmax<<<18, 256, 0, stream>>>(bpart, p);
    k_wx     <<<dim3(36, 2), 256, 0, stream>>>(x, p, wx);
    k_ov     <<<288, 256, 0, stream>>>(value_w, wx, ov);
    k_po     <<<288, 256, 0, stream>>>(proj_w, proj_b, ov, po);
    k_final  <<<2048, 256, 0, stream>>>(x, po, gamma, out);
}

// Round 2
// 87.125 us; speedup vs baseline: 1.1032x; 1.1032x over previous
//
#include <hip/hip_runtime.h>

// NovelKQRAttention — algebraically collapsed.
// energy = a[...,q,None] + b[...,None,k]; softmax over k => a cancels,
// attn = softmax_k(b) independent of q => deform-conv path is dead,
// attention output constant over spatial dims.
//
// Pipeline (5 kernels):
//   K1 k_bpart : per-block recompute kb[h,c]=sum_e bias*key_w (36-ch slice),
//                partial b[n,h,k] over its channel chunk -> bpart
//   K2 k_softmax: sum 16 chunks, softmax over k=1024 -> p
//   K3 k_wx    : wx[n,h,c] = sum_k p[n,h,k] * x_kv[n,c,k]
//   K4 k_proj  : ov = value_w @ wx (head-grouped), po = proj_w @ ov + proj_b
//   K5 k_final : out = gamma*po[n,o] + x

#define CCH 576
#define NHEADS 9
#define HW 4096   // 64*64
#define KHW 1024  // 32*32
#define WID 64
#define CH_CHUNKS 16
#define CH_PER 36   // 576/16

// ws float offsets
#define WS_BPART 0         // 2*16*9*1024 = 294912
#define WS_P     294912    // 2*9*1024    = 18432
#define WS_WX    313344    // 2*9*576     = 10368
#define WS_PO    323712    // 2*576       = 1152
// total 324864 floats = 1.27 MB

// grid (4 kblk, 2 n, 16 chunk), block 256.
__global__ void k_bpart(const float* __restrict__ x, const float* __restrict__ key_w,
                        const float* __restrict__ appr_bias, float* __restrict__ bpart) {
    int k  = blockIdx.x * 256 + threadIdx.x;   // 0..1023
    int n  = blockIdx.y;
    int ch = blockIdx.z;
    int c0 = ch * CH_PER;

    __shared__ float ab[CCH];
    __shared__ float kbs[NHEADS][CH_PER];
    for (int i = threadIdx.x; i < CCH; i += 256) ab[i] = appr_bias[i];
    __syncthreads();
    for (int t = threadIdx.x; t < NHEADS * CH_PER; t += 256) {
        int h = t / CH_PER, cl = t % CH_PER;
        float s = 0.f;
        #pragma unroll 8
        for (int e = 0; e < 64; ++e)
            s += ab[h * 64 + e] * key_w[(size_t)(h * 64 + e) * CCH + c0 + cl];
        kbs[h][cl] = s;
    }
    __syncthreads();

    int ky = k >> 5, kx = k & 31;
    const float* xb = x + (size_t)n * CCH * HW + (size_t)(ky * 2) * WID + kx * 2;
    float acc[NHEADS];
    #pragma unroll
    for (int h = 0; h < NHEADS; ++h) acc[h] = 0.f;
    for (int cl = 0; cl < CH_PER; ++cl) {
        float xv = xb[(size_t)(c0 + cl) * HW];
        #pragma unroll
        for (int h = 0; h < NHEADS; ++h) acc[h] += kbs[h][cl] * xv;
    }
    #pragma unroll
    for (int h = 0; h < NHEADS; ++h)
        bpart[(((size_t)n * CH_CHUNKS + ch) * NHEADS + h) * KHW + k] = acc[h];
}

// grid 18 (= n*9), block 256. Sum 16 chunks, softmax over k=1024, write p.
__global__ void k_softmax(const float* __restrict__ bpart, float* __restrict__ p) {
    int nh = blockIdx.x;
    int n = nh / NHEADS, h = nh % NHEADS;
    int tid = threadIdx.x;
    int wave = tid >> 6, lane = tid & 63;
    float s[4];
    #pragma unroll
    for (int j = 0; j < 4; ++j) {
        int k = tid + j * 256;
        float v = 0.f;
        #pragma unroll
        for (int ch = 0; ch < CH_CHUNKS; ++ch)
            v += bpart[(((size_t)n * CH_CHUNKS + ch) * NHEADS + h) * KHW + k];
        s[j] = v;
    }
    float m = fmaxf(fmaxf(s[0], s[1]), fmaxf(s[2], s[3]));
    #pragma unroll
    for (int off = 32; off >= 1; off >>= 1)
        m = fmaxf(m, __shfl_xor(m, off, 64));
    __shared__ float redm[4];
    if (lane == 0) redm[wave] = m;
    __syncthreads();
    m = fmaxf(fmaxf(redm[0], redm[1]), fmaxf(redm[2], redm[3]));
    float e[4], lsum = 0.f;
    #pragma unroll
    for (int j = 0; j < 4; ++j) { e[j] = __expf(s[j] - m); lsum += e[j]; }
    #pragma unroll
    for (int off = 32; off >= 1; off >>= 1)
        lsum += __shfl_xor(lsum, off, 64);
    __shared__ float reds[4];
    if (lane == 0) reds[wave] = lsum;
    __syncthreads();
    float inv = 1.f / (reds[0] + reds[1] + reds[2] + reds[3]);
    #pragma unroll
    for (int j = 0; j < 4; ++j)
        p[(size_t)nh * KHW + tid + j * 256] = e[j] * inv;
}

// grid (144 c-tiles, 2 n), block 256 (4 waves). Each wave: 1 channel, reduce over k.
__global__ void k_wx(const float* __restrict__ x, const float* __restrict__ p,
                     float* __restrict__ wx) {
    int n = blockIdx.y;
    __shared__ float ps[NHEADS * KHW];  // 36 KB
    for (int i = threadIdx.x; i < NHEADS * KHW; i += 256)
        ps[i] = p[(size_t)n * NHEADS * KHW + i];
    __syncthreads();
    int wave = threadIdx.x >> 6, lane = threadIdx.x & 63;
    int c = blockIdx.x * 4 + wave;
    const float* xb = x + ((size_t)n * CCH + c) * HW;
    float acc[NHEADS];
    #pragma unroll
    for (int h = 0; h < NHEADS; ++h) acc[h] = 0.f;
    #pragma unroll 4
    for (int j = 0; j < 16; ++j) {
        int k = lane + 64 * j;
        int ky = k >> 5, kx = k & 31;
        float xv = xb[(size_t)(ky * 2) * WID + kx * 2];
        #pragma unroll
        for (int h = 0; h < NHEADS; ++h) acc[h] += ps[h * KHW + k] * xv;
    }
    #pragma unroll
    for (int h = 0; h < NHEADS; ++h) {
        float v = acc[h];
        #pragma unroll
        for (int off = 32; off >= 1; off >>= 1)
            v += __shfl_xor(v, off, 64);
        if (lane == 0) wx[((size_t)n * NHEADS + h) * CCH + c] = v;
    }
}

// grid 2 (n), block 1024 (16 waves). ov in LDS, then po = proj_w@ov + proj_b.
__global__ void k_proj(const float* __restrict__ value_w, const float* __restrict__ proj_w,
                       const float* __restrict__ proj_b, const float* __restrict__ wx,
                       float* __restrict__ po) {
    int n = blockIdx.x;
    __shared__ float wxs[NHEADS * CCH];  // 20.7 KB
    __shared__ float ovs[CCH];
    for (int i = threadIdx.x; i < NHEADS * CCH; i += 1024)
        wxs[i] = wx[(size_t)n * NHEADS * CCH + i];
    __syncthreads();
    int wave = threadIdx.x >> 6, lane = threadIdx.x & 63;
    // stage A: ov[o] = sum_c value_w[o,c] * wx[h(o),c]
    for (int oi = 0; oi < CCH / 16; ++oi) {
        int o = wave * (CCH / 16) + oi;
        int h = o >> 6;
        float acc = 0.f;
        #pragma unroll
        for (int j = 0; j < 9; ++j) {
            int c = lane + 64 * j;
            acc += value_w[(size_t)o * CCH + c] * wxs[h * CCH + c];
        }
        #pragma unroll
        for (int off = 32; off >= 1; off >>= 1)
            acc += __shfl_xor(acc, off, 64);
        if (lane == 0) ovs[o] = acc;
    }
    __syncthreads();
    // stage B: po[o] = sum_c proj_w[o,c] * ov[c] + proj_b[o]
    for (int oi = 0; oi < CCH / 16; ++oi) {
        int o = wave * (CCH / 16) + oi;
        float acc = 0.f;
        #pragma unroll
        for (int j = 0; j < 9; ++j) {
            int c = lane + 64 * j;
            acc += proj_w[(size_t)o * CCH + c] * ovs[c];
        }
        #pragma unroll
        for (int off = 32; off >= 1; off >>= 1)
            acc += __shfl_xor(acc, off, 64);
        if (lane == 0) po[n * CCH + o] = acc + proj_b[o];
    }
}

// out[n,o,:,:] = gamma*po[n,o] + x ; vectorized float4 grid-stride
__global__ void k_final(const float* __restrict__ x, const float* __restrict__ po,
                        const float* __restrict__ gamma, float* __restrict__ out) {
    const size_t total4 = (size_t)2 * CCH * HW / 4;   // 1179648
    float g = gamma[0];
    const float4* x4 = (const float4*)x;
    float4* o4 = (float4*)out;
    for (size_t i = (size_t)blockIdx.x * blockDim.x + threadIdx.x; i < total4;
         i += (size_t)gridDim.x * blockDim.x) {
        int no = (int)((i * 4) / HW);       // n*CCH + o
        float base = g * po[no];
        float4 v = x4[i];
        v.x += base; v.y += base; v.z += base; v.w += base;
        o4[i] = v;
    }
}

extern "C" void kernel_launch(void* const* d_in, const int* in_sizes, int n_in,
                              void* d_out, int out_size, void* d_ws, size_t ws_size,
                              hipStream_t stream) {
    const float* x         = (const float*)d_in[0];
    const float* key_w     = (const float*)d_in[1];
    // d_in[2] offset_w, d_in[3] dconv_w, d_in[8] appr_bias_q: dead path (a cancels in softmax)
    const float* value_w   = (const float*)d_in[4];
    const float* proj_w    = (const float*)d_in[5];
    const float* proj_b    = (const float*)d_in[6];
    const float* appr_bias = (const float*)d_in[7];
    const float* gamma     = (const float*)d_in[9];
    float* out = (float*)d_out;

    float* ws    = (float*)d_ws;
    float* bpart = ws + WS_BPART;
    float* p     = ws + WS_P;
    float* wx    = ws + WS_WX;
    float* po    = ws + WS_PO;

    k_bpart  <<<dim3(4, 2, CH_CHUNKS), 256, 0, stream>>>(x, key_w, appr_bias, bpart);
    k_softmax<<<18, 256, 0, stream>>>(bpart, p);
    k_wx     <<<dim3(144, 2), 256, 0, stream>>>(x, p, wx);
    k_proj   <<<2, 1024, 0, stream>>>(value_w, proj_w, proj_b, wx, po);
    k_final  <<<2048, 256, 0, stream>>>(x, po, gamma, out);
}

// Round 3
// 37.510 us; speedup vs baseline: 2.5624x; 2.3227x over previous
//
#include <hip/hip_runtime.h>

// NovelKQRAttention — algebraically collapsed.
// energy = a[...,q,None] + b[...,None,k]; softmax over k => a cancels,
// attn = softmax_k(b) independent of q => deform-conv path is dead,
// attention output constant over spatial dims.
//
// Pipeline (6 kernels):
//   K1 k_bpart : per-block recompute kb[h,c]=sum_e bias*key_w (36-ch slice),
//                partial b[n,h,k] over its channel chunk -> bpart
//   K2 k_softmax: sum 16 chunks, softmax over k=1024 -> p
//   K3 k_wx    : wx[n,h,c] = sum_k p[n,h,k] * x_kv[n,c,k]
//   K4 k_ov    : ov[n,o] = value_w[o,:] . wx[n,h(o),:]   (1 wave/output, 288 blk)
//   K5 k_po    : po[n,o] = proj_w[o,:] . ov[n,:] + proj_b (1 wave/output, 288 blk)
//   K6 k_final : out = gamma*po[n,o] + x

#define CCH 576
#define NHEADS 9
#define HW 4096   // 64*64
#define KHW 1024  // 32*32
#define WID 64
#define CH_CHUNKS 16
#define CH_PER 36   // 576/16

// ws float offsets
#define WS_BPART 0         // 2*16*9*1024 = 294912
#define WS_P     294912    // 2*9*1024    = 18432
#define WS_WX    313344    // 2*9*576     = 10368
#define WS_OV    323712    // 2*576       = 1152
#define WS_PO    324864    // 2*576       = 1152
// total 326016 floats = 1.27 MB

// grid (4 kblk, 2 n, 16 chunk), block 256.
__global__ void k_bpart(const float* __restrict__ x, const float* __restrict__ key_w,
                        const float* __restrict__ appr_bias, float* __restrict__ bpart) {
    int k  = blockIdx.x * 256 + threadIdx.x;   // 0..1023
    int n  = blockIdx.y;
    int ch = blockIdx.z;
    int c0 = ch * CH_PER;

    __shared__ float ab[CCH];
    __shared__ float kbs[NHEADS][CH_PER];
    for (int i = threadIdx.x; i < CCH; i += 256) ab[i] = appr_bias[i];
    __syncthreads();
    for (int t = threadIdx.x; t < NHEADS * CH_PER; t += 256) {
        int h = t / CH_PER, cl = t % CH_PER;
        float s = 0.f;
        #pragma unroll 8
        for (int e = 0; e < 64; ++e)
            s += ab[h * 64 + e] * key_w[(size_t)(h * 64 + e) * CCH + c0 + cl];
        kbs[h][cl] = s;
    }
    __syncthreads();

    int ky = k >> 5, kx = k & 31;
    const float* xb = x + (size_t)n * CCH * HW + (size_t)(ky * 2) * WID + kx * 2;
    float acc[NHEADS];
    #pragma unroll
    for (int h = 0; h < NHEADS; ++h) acc[h] = 0.f;
    for (int cl = 0; cl < CH_PER; ++cl) {
        float xv = xb[(size_t)(c0 + cl) * HW];
        #pragma unroll
        for (int h = 0; h < NHEADS; ++h) acc[h] += kbs[h][cl] * xv;
    }
    #pragma unroll
    for (int h = 0; h < NHEADS; ++h)
        bpart[(((size_t)n * CH_CHUNKS + ch) * NHEADS + h) * KHW + k] = acc[h];
}

// grid 18 (= n*9), block 256. Sum 16 chunks, softmax over k=1024, write p.
__global__ void k_softmax(const float* __restrict__ bpart, float* __restrict__ p) {
    int nh = blockIdx.x;
    int n = nh / NHEADS, h = nh % NHEADS;
    int tid = threadIdx.x;
    int wave = tid >> 6, lane = tid & 63;
    float s[4];
    #pragma unroll
    for (int j = 0; j < 4; ++j) {
        int k = tid + j * 256;
        float v = 0.f;
        #pragma unroll
        for (int ch = 0; ch < CH_CHUNKS; ++ch)
            v += bpart[(((size_t)n * CH_CHUNKS + ch) * NHEADS + h) * KHW + k];
        s[j] = v;
    }
    float m = fmaxf(fmaxf(s[0], s[1]), fmaxf(s[2], s[3]));
    #pragma unroll
    for (int off = 32; off >= 1; off >>= 1)
        m = fmaxf(m, __shfl_xor(m, off, 64));
    __shared__ float redm[4];
    if (lane == 0) redm[wave] = m;
    __syncthreads();
    m = fmaxf(fmaxf(redm[0], redm[1]), fmaxf(redm[2], redm[3]));
    float e[4], lsum = 0.f;
    #pragma unroll
    for (int j = 0; j < 4; ++j) { e[j] = __expf(s[j] - m); lsum += e[j]; }
    #pragma unroll
    for (int off = 32; off >= 1; off >>= 1)
        lsum += __shfl_xor(lsum, off, 64);
    __shared__ float reds[4];
    if (lane == 0) reds[wave] = lsum;
    __syncthreads();
    float inv = 1.f / (reds[0] + reds[1] + reds[2] + reds[3]);
    #pragma unroll
    for (int j = 0; j < 4; ++j)
        p[(size_t)nh * KHW + tid + j * 256] = e[j] * inv;
}

// grid (144 c-tiles, 2 n), block 256 (4 waves). Each wave: 1 channel, reduce over k.
__global__ void k_wx(const float* __restrict__ x, const float* __restrict__ p,
                     float* __restrict__ wx) {
    int n = blockIdx.y;
    __shared__ float ps[NHEADS * KHW];  // 36 KB
    for (int i = threadIdx.x; i < NHEADS * KHW; i += 256)
        ps[i] = p[(size_t)n * NHEADS * KHW + i];
    __syncthreads();
    int wave = threadIdx.x >> 6, lane = threadIdx.x & 63;
    int c = blockIdx.x * 4 + wave;
    const float* xb = x + ((size_t)n * CCH + c) * HW;
    float acc[NHEADS];
    #pragma unroll
    for (int h = 0; h < NHEADS; ++h) acc[h] = 0.f;
    #pragma unroll 4
    for (int j = 0; j < 16; ++j) {
        int k = lane + 64 * j;
        int ky = k >> 5, kx = k & 31;
        float xv = xb[(size_t)(ky * 2) * WID + kx * 2];
        #pragma unroll
        for (int h = 0; h < NHEADS; ++h) acc[h] += ps[h * KHW + k] * xv;
    }
    #pragma unroll
    for (int h = 0; h < NHEADS; ++h) {
        float v = acc[h];
        #pragma unroll
        for (int off = 32; off >= 1; off >>= 1)
            v += __shfl_xor(v, off, 64);
        if (lane == 0) wx[((size_t)n * NHEADS + h) * CCH + c] = v;
    }
}

// one wave per output element; grid 288, block 256 (4 waves)
__global__ void k_ov(const float* __restrict__ value_w, const float* __restrict__ wx,
                     float* __restrict__ ov) {
    int g = blockIdx.x * 4 + (threadIdx.x >> 6);   // 0..1151
    int lane = threadIdx.x & 63;
    int n = g / CCH, o = g % CCH;
    int h = o >> 6;
    float acc = 0.f;
    #pragma unroll
    for (int j = 0; j < 9; ++j) {
        int c = lane + 64 * j;
        acc += value_w[(size_t)o * CCH + c] * wx[((size_t)n * NHEADS + h) * CCH + c];
    }
    #pragma unroll
    for (int off = 32; off >= 1; off >>= 1)
        acc += __shfl_xor(acc, off, 64);
    if (lane == 0) ov[n * CCH + o] = acc;
}

// one wave per output element; grid 288, block 256 (4 waves)
__global__ void k_po(const float* __restrict__ proj_w, const float* __restrict__ proj_b,
                     const float* __restrict__ ov, float* __restrict__ po) {
    int g = blockIdx.x * 4 + (threadIdx.x >> 6);
    int lane = threadIdx.x & 63;
    int n = g / CCH, o = g % CCH;
    float acc = 0.f;
    #pragma unroll
    for (int j = 0; j < 9; ++j) {
        int c = lane + 64 * j;
        acc += proj_w[(size_t)o * CCH + c] * ov[n * CCH + c];
    }
    #pragma unroll
    for (int off = 32; off >= 1; off >>= 1)
        acc += __shfl_xor(acc, off, 64);
    if (lane == 0) po[n * CCH + o] = acc + proj_b[o];
}

// out[n,o,:,:] = gamma*po[n,o] + x ; vectorized float4 grid-stride
__global__ void k_final(const float* __restrict__ x, const float* __restrict__ po,
                        const float* __restrict__ gamma, float* __restrict__ out) {
    const size_t total4 = (size_t)2 * CCH * HW / 4;   // 1179648
    float g = gamma[0];
    const float4* x4 = (const float4*)x;
    float4* o4 = (float4*)out;
    for (size_t i = (size_t)blockIdx.x * blockDim.x + threadIdx.x; i < total4;
         i += (size_t)gridDim.x * blockDim.x) {
        int no = (int)((i * 4) / HW);       // n*CCH + o
        float base = g * po[no];
        float4 v = x4[i];
        v.x += base; v.y += base; v.z += base; v.w += base;
        o4[i] = v;
    }
}

extern "C" void kernel_launch(void* const* d_in, const int* in_sizes, int n_in,
                              void* d_out, int out_size, void* d_ws, size_t ws_size,
                              hipStream_t stream) {
    const float* x         = (const float*)d_in[0];
    const float* key_w     = (const float*)d_in[1];
    // d_in[2] offset_w, d_in[3] dconv_w, d_in[8] appr_bias_q: dead path (a cancels in softmax)
    const float* value_w   = (const float*)d_in[4];
    const float* proj_w    = (const float*)d_in[5];
    const float* proj_b    = (const float*)d_in[6];
    const float* appr_bias = (const float*)d_in[7];
    const float* gamma     = (const float*)d_in[9];
    float* out = (float*)d_out;

    float* ws    = (float*)d_ws;
    float* bpart = ws + WS_BPART;
    float* p     = ws + WS_P;
    float* wx    = ws + WS_WX;
    float* ov    = ws + WS_OV;
    float* po    = ws + WS_PO;

    k_bpart  <<<dim3(4, 2, CH_CHUNKS), 256, 0, stream>>>(x, key_w, appr_bias, bpart);
    k_softmax<<<18, 256, 0, stream>>>(bpart, p);
    k_wx     <<<dim3(144, 2), 256, 0, stream>>>(x, p, wx);
    k_ov     <<<288, 256, 0, stream>>>(value_w, wx, ov);
    k_po     <<<288, 256, 0, stream>>>(proj_w, proj_b, ov, po);
    k_final  <<<2048, 256, 0, stream>>>(x, po, gamma, out);
}